// Round 6
// baseline (95.881 us; speedup 1.0000x reference)
//
#include <hip/hip_runtime.h>

// Problem constants (from the reference)
#define BB     256   // batch
#define S      64    // SIZE
#define EE     4096  // E
#define NROWS  17    // 1 + ADDITIONAL

// native clang vector type (HIP's float4 is a class; the nontemporal
// builtins require a true vector/scalar type)
typedef float f32x4 __attribute__((ext_vector_type(4)));

// ---------------------------------------------------------------------------
// Single fused kernel. Grid = BB*32 blocks (one per (batch, column-pair)),
// 256 threads. Structure per block:
//   1. issue the weight-input loads FIRST (offset, 16x bits, keys if needed)
//      -> they are the OLDEST vmem ops, so consuming them only needs
//         vmcnt(8) while the streaming loads stay in flight
//   2. issue the 8 nontemporal streaming input loads
//   3. per-wave weights compute: 17 ballots -> uint64 masks, products via
//      shfl_xor butterfly (all 64 lanes busy), normalize over all 17,
//      zero later duplicates, per-column W0/W1, shfl out the 4 scalars.
//      NO LDS, NO barriers -> no forced vmcnt(0) drains (R3's mistake).
//   4. FMA + 8 nontemporal stores to rows r0=sec+q, r1=sec+8+q.
//   5. blocks with pr==0 (wave 0) also write keys_out for their batch.
// Input read exactly once, output written exactly once.
// ---------------------------------------------------------------------------
__global__ __launch_bounds__(256) void split_fused_kernel(
    const float* __restrict__ input,    // [BB][S][EE]
    const float* __restrict__ keys,     // [BB][S]
    const float* __restrict__ offset,   // [BB][S]
    const int*   __restrict__ bits,     // [BB][16][S]
    float* __restrict__ out,            // [BB][S][EE]
    float* __restrict__ keys_out)       // [BB][S]
{
    const int blk  = blockIdx.x;
    const int b    = blk >> 5;
    const int pr   = blk & 31;
    const int tid  = threadIdx.x;
    const int lane = tid & 63;
    const int wv   = tid >> 6;

    const int sec = (pr >> 3) << 4;   // 0,16,32,48
    const int q   = pr & 7;
    const int c0  = sec + 2 * q;
    const int c1  = c0 + 1;
    const int r0  = sec + q;
    const int r1  = sec + 8 + q;

    // ---- 1. weight-input loads (oldest in the vmem queue) ----
    const float off = offset[b * S + lane];
    int bitv[16];
    #pragma unroll
    for (int j = 0; j < 16; ++j)
        bitv[j] = bits[((size_t)b * 16 + j) * S + lane];

    // keys only needed by the pr==0 block of each batch (uniform branch)
    const int kloc = lane & 15;
    const int ksec = lane & ~15;
    const int kt   = kloc >> 3;
    const int kq   = kloc & 7;
    const int kc0  = ksec + 2 * kq;
    const int kc1  = kc0 + 1;
    float k0 = 0.0f, k1 = 0.0f;
    if (pr == 0 && wv == 0) {
        k0 = keys[b * S + kc0];
        k1 = keys[b * S + kc1];
    }

    // ---- 2. streaming input loads (younger; weights compute overlaps) ----
    const f32x4* __restrict__ in0 = (const f32x4*)(input + ((size_t)b * S + c0) * EE);
    const f32x4* __restrict__ in1 = (const f32x4*)(input + ((size_t)b * S + c1) * EE);
    f32x4 x0[4], x1[4];
    #pragma unroll
    for (int it = 0; it < 4; ++it) {
        x0[it] = __builtin_nontemporal_load(&in0[tid + it * 256]);
        x1[it] = __builtin_nontemporal_load(&in1[tid + it * 256]);
    }

    // ---- 3. per-wave weights (no LDS, no barriers) ----
    unsigned long long mask[NROWS];
    mask[0] = __ballot((int)rintf(off) == 1);   // jnp.round = half-even
    #pragma unroll
    for (int j = 0; j < 16; ++j)
        mask[1 + j] = __ballot(bitv[j] == 1);

    const float one_m_off = 1.0f - off;
    float prob[NROWS];
    #pragma unroll
    for (int j = 0; j < NROWS; ++j) {
        float v = ((mask[j] >> lane) & 1ull) ? off : one_m_off;
        #pragma unroll
        for (int d = 1; d < 64; d <<= 1)
            v *= __shfl_xor(v, d, 64);
        prob[j] = v;            // all lanes hold the full product
    }

    float sum = 0.0f;
    #pragma unroll
    for (int j = 0; j < NROWS; ++j) sum += prob[j];
    const float inv = 1.0f / sum;
    #pragma unroll
    for (int j = 0; j < NROWS; ++j) {
        bool dup = false;
        #pragma unroll
        for (int k = 0; k < NROWS; ++k)
            if (k < j) dup |= (mask[k] == mask[j]);
        prob[j] = dup ? 0.0f : prob[j] * inv;
    }

    // per-column split weights (lane = column)
    float w0 = 0.0f, w1 = 0.0f;
    #pragma unroll
    for (int j = 0; j < NROWS; ++j) {
        if ((mask[j] >> lane) & 1ull) w1 += prob[j]; else w0 += prob[j];
    }

    // block-uniform 2x2 weights via shuffles
    const float wa0 = __shfl(w0, c0, 64), wb0 = __shfl(w0, c1, 64);
    const float wa1 = __shfl(w1, c0, 64), wb1 = __shfl(w1, c1, 64);

    // ---- 5. keys_out (one wave of one block per batch) ----
    if (pr == 0 && wv == 0) {
        const float ka0 = __shfl(w0, kc0, 64), ka1 = __shfl(w1, kc0, 64);
        const float kb0 = __shfl(w0, kc1, 64), kb1 = __shfl(w1, kc1, 64);
        const float wa = kt ? ka1 : ka0;
        const float wb = kt ? kb1 : kb0;
        keys_out[b * S + lane] = wa * k0 + wb * k1;
    }

    // ---- 4. apply + nontemporal stores ----
    f32x4* __restrict__ o0 = (f32x4*)(out + ((size_t)b * S + r0) * EE);
    f32x4* __restrict__ o1 = (f32x4*)(out + ((size_t)b * S + r1) * EE);

    #pragma unroll
    for (int it = 0; it < 4; ++it) {
        const int idx = tid + it * 256;
        f32x4 y0, y1;
        y0.x = wa0 * x0[it].x + wb0 * x1[it].x;
        y0.y = wa0 * x0[it].y + wb0 * x1[it].y;
        y0.z = wa0 * x0[it].z + wb0 * x1[it].z;
        y0.w = wa0 * x0[it].w + wb0 * x1[it].w;
        y1.x = wa1 * x0[it].x + wb1 * x1[it].x;
        y1.y = wa1 * x0[it].y + wb1 * x1[it].y;
        y1.z = wa1 * x0[it].z + wb1 * x1[it].z;
        y1.w = wa1 * x0[it].w + wb1 * x1[it].w;
        __builtin_nontemporal_store(y0, &o0[idx]);
        __builtin_nontemporal_store(y1, &o1[idx]);
    }
}

extern "C" void kernel_launch(void* const* d_in, const int* in_sizes, int n_in,
                              void* d_out, int out_size, void* d_ws, size_t ws_size,
                              hipStream_t stream) {
    const float* input  = (const float*)d_in[0];   // [256,64,4096] f32
    const float* keys   = (const float*)d_in[1];   // [256,64] f32
    const float* offset = (const float*)d_in[2];   // [256,64] f32
    const int*   bits   = (const int*)  d_in[3];   // [256,16,64] i32

    float* out      = (float*)d_out;                  // [256,64,4096]
    float* keys_out = out + (size_t)BB * S * EE;      // [256,64]

    split_fused_kernel<<<BB * 32, 256, 0, stream>>>(input, keys, offset, bits,
                                                    out, keys_out);
}